// Round 12
// baseline (548.857 us; speedup 1.0000x reference)
//
#include <hip/hip_runtime.h>
#include <stdint.h>
#include <math.h>

#define NTOK 2048
#define HDIM 2048
#define FDIM 1024
#define NEXP 32
#define TOPK 4
#define NGRP 4
#define CAP  512

typedef _Float16 f16;
typedef _Float16 half8 __attribute__((ext_vector_type(8)));
typedef _Float16 half2v __attribute__((ext_vector_type(2)));
typedef float f32x4 __attribute__((ext_vector_type(4)));

__device__ __forceinline__ int swz3(int n) { return (n ^ (n >> 2)) & 3; }

// ---------------- fused gate + convert ----------------
__global__ __launch_bounds__(256) void gateconv_kernel(const float* __restrict__ x,
                                                       const float* __restrict__ gw,
                                                       const float* __restrict__ gb,
                                                       int* __restrict__ tidx,
                                                       float* __restrict__ tw,
                                                       f16* __restrict__ xbt) {
  int t = blockIdx.x;
  int tid = threadIdx.x;
  int e = tid >> 3, p = tid & 7;
  const f32x4* xr = (const f32x4*)(x + (size_t)t * HDIM);
  const f32x4* wr = (const f32x4*)(gw + (size_t)e * HDIM);
  float s = 0.f;
  for (int c = 0; c < 64; c++) {
    f32x4 a = xr[p + c * 8], w = wr[p + c * 8];
    s += a[0] * w[0] + a[1] * w[1] + a[2] * w[2] + a[3] * w[3];
  }
  s += __shfl_down(s, 4, 8);
  s += __shfl_down(s, 2, 8);
  s += __shfl_down(s, 1, 8);
  __shared__ float lg[NEXP];
  if (p == 0) lg[e] = s;

  {
    int c8 = tid * 8;
    const float* pp = x + (size_t)t * HDIM + c8;
    f32x4 a = *(const f32x4*)pp;
    f32x4 b = *(const f32x4*)(pp + 4);
    half8 v;
    v[0] = (f16)a[0]; v[1] = (f16)a[1]; v[2] = (f16)a[2]; v[3] = (f16)a[3];
    v[4] = (f16)b[0]; v[5] = (f16)b[1]; v[6] = (f16)b[2]; v[7] = (f16)b[3];
    *(half8*)((char*)xbt + (size_t)(c8 >> 5) * 131072 + t * 64 + (c8 & 31) * 2) = v;
  }

  __syncthreads();
  if (tid == 0) {
    float sc[NEXP], scb[NEXP];
    for (int i = 0; i < NEXP; i++) {
      sc[i] = 1.f / (1.f + expf(-lg[i]));
      scb[i] = sc[i] + gb[i];
    }
    float gs[NGRP];
    for (int g = 0; g < NGRP; g++) {
      float m1 = -1e30f, m2 = -1e30f;
      for (int j = 0; j < 8; j++) {
        float v = scb[g * 8 + j];
        if (v > m1) { m2 = m1; m1 = v; }
        else if (v > m2) m2 = v;
      }
      gs[g] = m1 + m2;
    }
    int g1 = 0; float bv = gs[0];
    for (int g = 1; g < NGRP; g++) if (gs[g] > bv) { bv = gs[g]; g1 = g; }
    int g2 = -1; bv = -1e30f;
    for (int g = 0; g < NGRP; g++) if (g != g1 && gs[g] > bv) { bv = gs[g]; g2 = g; }
    float cand[NEXP];
    for (int i = 0; i < NEXP; i++) {
      int g = i >> 3;
      cand[i] = (g == g1 || g == g2) ? scb[i] : 0.0f;
    }
    int isel[TOPK]; float wsel[TOPK]; float wsum = 0.f;
    bool used[NEXP] = {};
    for (int k = 0; k < TOPK; k++) {
      int best = 0; float bw = -1e30f;
      for (int i = 0; i < NEXP; i++)
        if (!used[i] && cand[i] > bw) { bw = cand[i]; best = i; }
      used[best] = true;
      isel[k] = best;
      wsel[k] = sc[best];
      wsum += wsel[k];
    }
    float inv = 2.0f / (wsum + 1e-20f);
    for (int k = 0; k < TOPK; k++) {
      tidx[t * TOPK + k] = isel[k];
      tw[t * TOPK + k] = wsel[k] * inv;
    }
  }
}

// ---------------- dispatch ----------------
__global__ __launch_bounds__(256) void dispatch_kernel(const int* __restrict__ tidx,
                                                       const float* __restrict__ tw,
                                                       int* __restrict__ tok,
                                                       float* __restrict__ wt,
                                                       int* __restrict__ cnt) {
  int e = blockIdx.x, tid = threadIdx.x, wv = tid >> 6, lane = tid & 63;
  __shared__ int wsum[4];
  __shared__ int sbase;
  if (tid == 0) sbase = 0;
  __syncthreads();
  for (int c = 0; c < (NTOK * TOPK) / 256; c++) {
    int i = c * 256 + tid;
    int fe = tidx[i];
    bool flag = (fe == e);
    unsigned long long b = __ballot(flag ? 1 : 0);
    int lr = __popcll(b & ((1ull << lane) - 1ull));
    if (lane == 0) wsum[wv] = __popcll(b);
    __syncthreads();
    int off = 0;
    for (int w2 = 0; w2 < wv; w2++) off += wsum[w2];
    int tot = wsum[0] + wsum[1] + wsum[2] + wsum[3];
    int base = sbase;
    if (flag) {
      int pos = base + off + lr;
      if (pos < CAP) {
        tok[e * CAP + pos] = i >> 2;
        wt[e * CAP + pos] = tw[i];
      }
    }
    __syncthreads();
    if (tid == 0) sbase = base + tot;
  }
  __syncthreads();
  if (tid == 0) cnt[e] = min(sbase, CAP);
}

// ---------------- scan: offs = exclusive prefix of cnt ----------------
__global__ void scan_kernel(const int* __restrict__ cnt, int* __restrict__ offs) {
  if (threadIdx.x == 0) {
    int s = 0;
    for (int e = 0; e < NEXP; e++) { offs[e] = s; s += cnt[e]; }
  }
}

// ---------------- gather: compact xg[e] = [64kt][cnt_e][32k] fp16 ----------------
__global__ __launch_bounds__(256) void gather_kernel(const f16* __restrict__ xbt,
                                                     const int* __restrict__ tok,
                                                     const int* __restrict__ cnt,
                                                     const int* __restrict__ offs,
                                                     f16* __restrict__ xg) {
  int bid = blockIdx.x;
  int t = bid & 63, e = bid >> 6;
  int cn = cnt[e];
  int tid = threadIdx.x;
  char* dst = (char*)xg + (size_t)offs[e] * 4096 + (size_t)t * cn * 64;
  const char* srcb = (const char*)xbt + (size_t)t * 131072;
  for (int s = tid; s < cn; s += 256) {
    const uint4* sp = (const uint4*)(srcb + (size_t)tok[e * CAP + s] * 64);
    uint4 v0 = sp[0], v1 = sp[1], v2 = sp[2], v3 = sp[3];
    uint4* dp = (uint4*)(dst + s * 64);
    dp[0] = v0; dp[1] = v1; dp[2] = v2; dp[3] = v3;
  }
}

// ---------------- 128x128 single-mat GEMM core, af double-buffered ----------------
#define SYNC() { asm volatile("s_waitcnt lgkmcnt(0)" ::: "memory"); __builtin_amdgcn_s_barrier(); }

__device__ __forceinline__ void core128(const char* __restrict__ Ab, int tsA, int NKt,
                                        const float* __restrict__ Bb, int ND,
                                        char* lds, f32x4 (&acc)[4][4]) {
  int tid = threadIdx.x, lane = tid & 63, wv = tid >> 6;
  int wn = (wv & 1) * 64;
  int wm = (wv >> 1) * 64;
  int kgrp = (tid >> 5) * 2;          // even k-pair base (0..14)
  int n4 = (tid & 31) * 4;            // B col group
  const float* B0r = Bb + (size_t)kgrp * ND + n4;
  const float* B1r = Bb + (size_t)(kgrp + 16) * ND + n4;

  unsigned aoff[4];
#pragma unroll
  for (int mf = 0; mf < 4; mf++)
    aoff[mf] = (wm + mf * 16 + (lane & 15)) * 64 + ((lane >> 4) << 4);

  int wo0[4], wo1[4];
#pragma unroll
  for (int q = 0; q < 4; q++) {
    int n = n4 + q;
    wo0[q] = n * 64 + ((((kgrp) >> 3) ^ swz3(n)) << 4) + (kgrp & 7) * 2;
    wo1[q] = n * 64 + ((((kgrp + 16) >> 3) ^ swz3(n)) << 4) + (kgrp & 7) * 2;
  }

  half8 afA[4], afB[4], bf[4];
  f32x4 E0, E1, E2, E3, O0, O1, O2, O3;

#define LOADB(tt, S0, S1, S2, S3) { size_t _o = (size_t)(tt) * 32 * ND; \
    S0 = *(const f32x4*)(B0r + _o); S1 = *(const f32x4*)(B0r + _o + ND); \
    S2 = *(const f32x4*)(B1r + _o); S3 = *(const f32x4*)(B1r + _o + ND); }

#define WRITEB(S0, S1, S2, S3, par) { char* _b = lds + (par) * 8192; \
    _Pragma("unroll") for (int _q = 0; _q < 4; _q++) { \
      half2v _h0; _h0[0] = (f16)S0[_q]; _h0[1] = (f16)S1[_q]; \
      *(half2v*)(_b + wo0[_q]) = _h0; \
      half2v _h1; _h1[0] = (f16)S2[_q]; _h1[1] = (f16)S3[_q]; \
      *(half2v*)(_b + wo1[_q]) = _h1; } }

#define BFREAD(par) { _Pragma("unroll") for (int _f = 0; _f < 4; _f++) { \
      int _n = wn + _f * 16 + (lane & 15); \
      bf[_f] = *(const half8*)(lds + (par) * 8192 + _n * 64 + (((lane >> 4) ^ swz3(_n)) << 4)); } }

#define LOADA(tt, AF) { _Pragma("unroll") for (int _m = 0; _m < 4; _m++) \
      AF[_m] = *(const half8*)(Ab + (size_t)(tt) * tsA + aoff[_m]); }

#define DOMFMA(AF) { _Pragma("unroll") for (int _m = 0; _m < 4; _m++) \
      _Pragma("unroll") for (int _f = 0; _f < 4; _f++) \
        acc[_m][_f] = __builtin_amdgcn_mfma_f32_16x16x32_f16(AF[_m], bf[_f], acc[_m][_f], 0, 0, 0); }

  LOADB(0, E0, E1, E2, E3)
  LOADB(1, O0, O1, O2, O3)
  WRITEB(E0, E1, E2, E3, 0)
  LOADA(0, afA)
  SYNC()

  for (int t = 0; t < NKt; t += 2) {
    BFREAD(0)
    LOADA(t + 1, afB)                     // full-tile lead for A(t+1)
    WRITEB(O0, O1, O2, O3, 1)
    if (t + 2 < NKt) LOADB(t + 2, E0, E1, E2, E3)
    DOMFMA(afA)
    SYNC()
    BFREAD(1)
    if (t + 2 < NKt) {
      LOADA(t + 2, afA)
      WRITEB(E0, E1, E2, E3, 0)
      if (t + 3 < NKt) LOADB(t + 3, O0, O1, O2, O3)
    }
    DOMFMA(afB)
    if (t + 2 < NKt) SYNC()
  }

#undef LOADB
#undef WRITEB
#undef BFREAD
#undef LOADA
#undef DOMFMA
}

// ---------------- fused up: routed g/u (2048 blk) + shared g/u (512 blk) ----------------
__global__ __launch_bounds__(256, 2) void fused_up_kernel(
    const f16* __restrict__ xg, const f16* __restrict__ xbt,
    const float* __restrict__ w1, const float* __restrict__ w3,
    const float* __restrict__ sg, const float* __restrict__ su,
    f16* __restrict__ hg, f16* __restrict__ hu,
    f16* __restrict__ hsg, f16* __restrict__ hsu,
    const int* __restrict__ cnt, const int* __restrict__ offs) {
  __shared__ __align__(16) char lds[16384];
  int bid = blockIdx.x;
  int tid = threadIdx.x, lane = tid & 63, wv = tid >> 6;
  int wm = (wv >> 1) * 64, wn = (wv & 1) * 64, koff = (lane >> 4) << 2;

  f32x4 acc[4][4];
#pragma unroll
  for (int mf = 0; mf < 4; mf++)
#pragma unroll
    for (int nf = 0; nf < 4; nf++) acc[mf][nf] = (f32x4){0.f, 0.f, 0.f, 0.f};

  if (bid < 2048) {
    int elo = bid & 7, n = (bid >> 3) & 7, m = (bid >> 6) & 3, ehi = (bid >> 8) & 3, mat = bid >> 10;
    int e = elo + ehi * 8;
    int ce = cnt[e];
    int m0 = m * 128;
    if (m0 >= ce) return;
    int oe = offs[e];
    const char* Ab = (const char*)xg + (size_t)oe * 4096 + m0 * 64;
    const float* B = (mat ? w3 : w1) + (size_t)e * 2048 * 1024 + n * 128;
    core128(Ab, ce * 64, 64, B, 1024, lds, acc);
    char* Hb = (char*)(mat ? hu : hg) + (size_t)oe * 2048;
    size_t kts = (size_t)ce * 64;
#pragma unroll
    for (int mf = 0; mf < 4; mf++)
#pragma unroll
      for (int j = 0; j < 4; j++) {
        int gs = m0 + wm + mf * 16 + koff + j;
        if (gs < ce) {
#pragma unroll
          for (int nf = 0; nf < 4; nf++) {
            int gc = n * 128 + wn + nf * 16 + (lane & 15);
            *(f16*)(Hb + (size_t)(gc >> 5) * kts + gs * 64 + (gc & 31) * 2) = (f16)acc[mf][nf][j];
          }
        }
      }
  } else {
    int b2 = bid - 2048;
    int mat = b2 >> 8, rem = b2 & 255, m = rem >> 4, n = rem & 15;
    int m0 = m * 128;
    const char* Ab = (const char*)xbt + m0 * 64;
    const float* B = (mat ? su : sg) + n * 128;
    core128(Ab, 131072, 64, B, 2048, lds, acc);
    char* Hb = (char*)(mat ? hsu : hsg);
#pragma unroll
    for (int mf = 0; mf < 4; mf++)
#pragma unroll
      for (int j = 0; j < 4; j++) {
        int gs = m0 + wm + mf * 16 + koff + j;
#pragma unroll
        for (int nf = 0; nf < 4; nf++) {
          int gc = n * 128 + wn + nf * 16 + (lane & 15);
          *(f16*)(Hb + (size_t)(gc >> 5) * 131072 + gs * 64 + (gc & 31) * 2) = (f16)acc[mf][nf][j];
        }
      }
  }
}

// ---------------- combine: h = silu(g) * u (elementwise, layout-agnostic) ----------------
__global__ __launch_bounds__(256) void combine_kernel(
    const f16* __restrict__ hg, const f16* __restrict__ hu, f16* __restrict__ hbuf,
    const f16* __restrict__ hsg, const f16* __restrict__ hsu, f16* __restrict__ hs) {
  size_t i = ((size_t)blockIdx.x * 256 + threadIdx.x) * 8;
  const f16 *gp, *up;
  f16* op;
  if (i < 8388608) { gp = hg + i; up = hu + i; op = hbuf + i; }
  else { size_t j = i - 8388608; gp = hsg + j; up = hsu + j; op = hs + j; }
  half8 g = *(const half8*)gp;
  half8 u = *(const half8*)up;
  half8 o;
#pragma unroll
  for (int k = 0; k < 8; k++) {
    float gv = (float)g[k];
    float uv = (float)u[k];
    o[k] = (f16)(gv / (1.f + expf(-gv)) * uv);
  }
  *(half8*)op = o;
}

// ---------------- fused down: routed (2048 blk) + shared (256 blk), atomics into out ----------------
__global__ __launch_bounds__(256, 2) void fused_down_kernel(
    const f16* __restrict__ hbuf, const f16* __restrict__ hs,
    const float* __restrict__ w2, const float* __restrict__ sd,
    float* __restrict__ out, const int* __restrict__ tok,
    const float* __restrict__ wt, const int* __restrict__ cnt,
    const int* __restrict__ offs) {
  __shared__ __align__(16) char lds[16384];
  int bid = blockIdx.x;
  int tid = threadIdx.x, lane = tid & 63, wv = tid >> 6;
  int wm = (wv >> 1) * 64, wn = (wv & 1) * 64, koff = (lane >> 4) << 2;

  f32x4 acc[4][4];
#pragma unroll
  for (int mf = 0; mf < 4; mf++)
#pragma unroll
    for (int nf = 0; nf < 4; nf++) acc[mf][nf] = (f32x4){0.f, 0.f, 0.f, 0.f};

  if (bid < 2048) {
    int elo = bid & 7, n = (bid >> 3) & 15, m = (bid >> 7) & 3, ehi = (bid >> 9) & 3;
    int e = elo + ehi * 8;
    int ce = cnt[e];
    int m0 = m * 128;
    if (m0 >= ce) return;
    int oe = offs[e];
    const char* Ab = (const char*)hbuf + (size_t)oe * 2048 + m0 * 64;
    const float* B = w2 + (size_t)e * 1024 * 2048 + n * 128;
    core128(Ab, ce * 64, 32, B, 2048, lds, acc);
    const int* tokp = tok + e * CAP;
    const float* wtp = wt + e * CAP;
#pragma unroll
    for (int mf = 0; mf < 4; mf++)
#pragma unroll
      for (int j = 0; j < 4; j++) {
        int gs = m0 + wm + mf * 16 + koff + j;
        if (gs < ce) {
          int tk = tokp[gs];
          float w = wtp[gs];
#pragma unroll
          for (int nf = 0; nf < 4; nf++) {
            int gc = n * 128 + wn + nf * 16 + (lane & 15);
            atomicAdd(out + (size_t)tk * HDIM + gc, acc[mf][nf][j] * w);
          }
        }
      }
  } else {
    int b2 = bid - 2048;
    int m = b2 >> 4, n = b2 & 15;
    int m0 = m * 128;
    const char* Ab = (const char*)hs + m0 * 64;
    const float* B = sd + n * 128;
    core128(Ab, 131072, 64, B, 2048, lds, acc);
#pragma unroll
    for (int mf = 0; mf < 4; mf++)
#pragma unroll
      for (int j = 0; j < 4; j++) {
        int gs = m0 + wm + mf * 16 + koff + j;
#pragma unroll
        for (int nf = 0; nf < 4; nf++) {
          int gc = n * 128 + wn + nf * 16 + (lane & 15);
          atomicAdd(out + (size_t)gs * HDIM + gc, acc[mf][nf][j]);
        }
      }
  }
}

// ---------------- launch ----------------
extern "C" void kernel_launch(void* const* d_in, const int* in_sizes, int n_in,
                              void* d_out, int out_size, void* d_ws, size_t ws_size,
                              hipStream_t stream) {
  const float* x  = (const float*)d_in[0];
  const float* gw = (const float*)d_in[1];
  const float* gb = (const float*)d_in[2];
  const float* w1 = (const float*)d_in[3];
  const float* w2 = (const float*)d_in[4];
  const float* w3 = (const float*)d_in[5];
  const float* sg = (const float*)d_in[6];
  const float* su = (const float*)d_in[7];
  const float* sd = (const float*)d_in[8];
  float* out = (float*)d_out;
  char* ws = (char*)d_ws;

  f16*   xbt  = (f16*)(ws);                  // 8 MB
  f16*   hsg  = (f16*)(ws + 8388608);        // 8 MB
  f16*   hsu  = (f16*)(ws + 16777216);       // 8 MB
  f16*   hs   = (f16*)(ws + 25165824);       // 8 MB
  f16*   hg   = (f16*)(ws + 33554432);       // 16 MB (8192 x 1024 f16)
  f16*   hu   = (f16*)(ws + 50331648);       // 16 MB
  f16*   xg   = (f16*)(ws + 67108864);       // 32 MB + slack (compact gathered A)
  f16*   hbuf = (f16*)(ws + 67108864);       // 16 MB (aliases xg; disjoint lifetime)
  int*   tok  = (int*)(ws + 101711872);      // 64 KB
  float* wt   = (float*)(ws + 101777408);    // 64 KB
  int*   tidx = (int*)(ws + 101842944);      // 32 KB
  float* tw   = (float*)(ws + 101875712);    // 32 KB
  int*   cnt  = (int*)(ws + 101908480);
  int*   offs = (int*)(ws + 101908608);

  gateconv_kernel<<<2048, 256, 0, stream>>>(x, gw, gb, tidx, tw, xbt);
  dispatch_kernel<<<32, 256, 0, stream>>>(tidx, tw, tok, wt, cnt);
  scan_kernel<<<1, 32, 0, stream>>>(cnt, offs);
  gather_kernel<<<2048, 256, 0, stream>>>(xbt, tok, cnt, offs, xg);

  // up: routed g/u (4m x 8n x 32e x 2mat = 2048) + shared g/u (16m x 16n x 2mat = 512)
  fused_up_kernel<<<2560, 256, 0, stream>>>(xg, xbt, w1, w3, sg, su,
                                            hg, hu, hsg, hsu, cnt, offs);
  // h = silu(g)*u for routed (16 MB region) + shared (8 MB region)
  combine_kernel<<<6144, 256, 0, stream>>>(hg, hu, hbuf, hsg, hsu, hs);

  hipMemsetAsync(out, 0, (size_t)out_size * sizeof(float), stream);
  // down: routed (4m x 16n x 32e = 2048) + shared (16m x 16n = 256), atomics
  fused_down_kernel<<<2304, 256, 0, stream>>>(hbuf, hs, w2, sd, out, tok, wt, cnt, offs);
}

// Round 13
// 518.780 us; speedup vs baseline: 1.0580x; 1.0580x over previous
//
#include <hip/hip_runtime.h>
#include <stdint.h>
#include <math.h>

#define NTOK 2048
#define HDIM 2048
#define FDIM 1024
#define NEXP 32
#define TOPK 4
#define NGRP 4
#define CAP  512

typedef _Float16 f16;
typedef _Float16 half8 __attribute__((ext_vector_type(8)));
typedef _Float16 half2v __attribute__((ext_vector_type(2)));
typedef float f32x4 __attribute__((ext_vector_type(4)));

__device__ __forceinline__ int swz3(int n) { return (n ^ (n >> 2)) & 3; }

// ---------------- fused gate + convert ----------------
__global__ __launch_bounds__(256) void gateconv_kernel(const float* __restrict__ x,
                                                       const float* __restrict__ gw,
                                                       const float* __restrict__ gb,
                                                       int* __restrict__ tidx,
                                                       float* __restrict__ tw,
                                                       f16* __restrict__ xbt) {
  int t = blockIdx.x;
  int tid = threadIdx.x;
  int e = tid >> 3, p = tid & 7;
  const f32x4* xr = (const f32x4*)(x + (size_t)t * HDIM);
  const f32x4* wr = (const f32x4*)(gw + (size_t)e * HDIM);
  float s = 0.f;
  for (int c = 0; c < 64; c++) {
    f32x4 a = xr[p + c * 8], w = wr[p + c * 8];
    s += a[0] * w[0] + a[1] * w[1] + a[2] * w[2] + a[3] * w[3];
  }
  s += __shfl_down(s, 4, 8);
  s += __shfl_down(s, 2, 8);
  s += __shfl_down(s, 1, 8);
  __shared__ float lg[NEXP];
  if (p == 0) lg[e] = s;

  {
    int c8 = tid * 8;
    const float* pp = x + (size_t)t * HDIM + c8;
    f32x4 a = *(const f32x4*)pp;
    f32x4 b = *(const f32x4*)(pp + 4);
    half8 v;
    v[0] = (f16)a[0]; v[1] = (f16)a[1]; v[2] = (f16)a[2]; v[3] = (f16)a[3];
    v[4] = (f16)b[0]; v[5] = (f16)b[1]; v[6] = (f16)b[2]; v[7] = (f16)b[3];
    *(half8*)((char*)xbt + (size_t)(c8 >> 5) * 131072 + t * 64 + (c8 & 31) * 2) = v;
  }

  __syncthreads();
  if (tid == 0) {
    float sc[NEXP], scb[NEXP];
    for (int i = 0; i < NEXP; i++) {
      sc[i] = 1.f / (1.f + expf(-lg[i]));
      scb[i] = sc[i] + gb[i];
    }
    float gs[NGRP];
    for (int g = 0; g < NGRP; g++) {
      float m1 = -1e30f, m2 = -1e30f;
      for (int j = 0; j < 8; j++) {
        float v = scb[g * 8 + j];
        if (v > m1) { m2 = m1; m1 = v; }
        else if (v > m2) m2 = v;
      }
      gs[g] = m1 + m2;
    }
    int g1 = 0; float bv = gs[0];
    for (int g = 1; g < NGRP; g++) if (gs[g] > bv) { bv = gs[g]; g1 = g; }
    int g2 = -1; bv = -1e30f;
    for (int g = 0; g < NGRP; g++) if (g != g1 && gs[g] > bv) { bv = gs[g]; g2 = g; }
    float cand[NEXP];
    for (int i = 0; i < NEXP; i++) {
      int g = i >> 3;
      cand[i] = (g == g1 || g == g2) ? scb[i] : 0.0f;
    }
    int isel[TOPK]; float wsel[TOPK]; float wsum = 0.f;
    bool used[NEXP] = {};
    for (int k = 0; k < TOPK; k++) {
      int best = 0; float bw = -1e30f;
      for (int i = 0; i < NEXP; i++)
        if (!used[i] && cand[i] > bw) { bw = cand[i]; best = i; }
      used[best] = true;
      isel[k] = best;
      wsel[k] = sc[best];
      wsum += wsel[k];
    }
    float inv = 2.0f / (wsum + 1e-20f);
    for (int k = 0; k < TOPK; k++) {
      tidx[t * TOPK + k] = isel[k];
      tw[t * TOPK + k] = wsel[k] * inv;
    }
  }
}

// ---------------- dispatch ----------------
__global__ __launch_bounds__(256) void dispatch_kernel(const int* __restrict__ tidx,
                                                       const float* __restrict__ tw,
                                                       int* __restrict__ tok,
                                                       float* __restrict__ wt,
                                                       int* __restrict__ cnt) {
  int e = blockIdx.x, tid = threadIdx.x, wv = tid >> 6, lane = tid & 63;
  __shared__ int wsum[4];
  __shared__ int sbase;
  if (tid == 0) sbase = 0;
  __syncthreads();
  for (int c = 0; c < (NTOK * TOPK) / 256; c++) {
    int i = c * 256 + tid;
    int fe = tidx[i];
    bool flag = (fe == e);
    unsigned long long b = __ballot(flag ? 1 : 0);
    int lr = __popcll(b & ((1ull << lane) - 1ull));
    if (lane == 0) wsum[wv] = __popcll(b);
    __syncthreads();
    int off = 0;
    for (int w2 = 0; w2 < wv; w2++) off += wsum[w2];
    int tot = wsum[0] + wsum[1] + wsum[2] + wsum[3];
    int base = sbase;
    if (flag) {
      int pos = base + off + lr;
      if (pos < CAP) {
        tok[e * CAP + pos] = i >> 2;
        wt[e * CAP + pos] = tw[i];
      }
    }
    __syncthreads();
    if (tid == 0) sbase = base + tot;
  }
  __syncthreads();
  if (tid == 0) cnt[e] = min(sbase, CAP);
}

// ---------------- scan ----------------
__global__ void scan_kernel(const int* __restrict__ cnt, int* __restrict__ offs) {
  if (threadIdx.x == 0) {
    int s = 0;
    for (int e = 0; e < NEXP; e++) { offs[e] = s; s += cnt[e]; }
  }
}

// ---------------- gather: compact xg[e] = [64kt][cnt_e][32k] fp16 ----------------
__global__ __launch_bounds__(256) void gather_kernel(const f16* __restrict__ xbt,
                                                     const int* __restrict__ tok,
                                                     const int* __restrict__ cnt,
                                                     const int* __restrict__ offs,
                                                     f16* __restrict__ xg) {
  int bid = blockIdx.x;
  int t = bid & 63, e = bid >> 6;
  int cn = cnt[e];
  int tid = threadIdx.x;
  char* dst = (char*)xg + (size_t)offs[e] * 4096 + (size_t)t * cn * 64;
  const char* srcb = (const char*)xbt + (size_t)t * 131072;
  for (int s = tid; s < cn; s += 256) {
    const uint4* sp = (const uint4*)(srcb + (size_t)tok[e * CAP + s] * 64);
    uint4 v0 = sp[0], v1 = sp[1], v2 = sp[2], v3 = sp[3];
    uint4* dp = (uint4*)(dst + s * 64);
    dp[0] = v0; dp[1] = v1; dp[2] = v2; dp[3] = v3;
  }
}

// ---------------- 128x128 single-mat GEMM core, 4-way-max LDS writes ----------------
#define SYNC() { asm volatile("s_waitcnt lgkmcnt(0)" ::: "memory"); __builtin_amdgcn_s_barrier(); }

__device__ __forceinline__ void core128(const char* __restrict__ Ab, int tsA, int NKt,
                                        const float* __restrict__ Bb, int ND,
                                        char* lds, f32x4 (&acc)[4][4]) {
  int tid = threadIdx.x, lane = tid & 63, wv = tid >> 6;
  int wn = (wv & 1) * 64;
  int wm = (wv >> 1) * 64;
  // B staging map: lane owns k-pair kg (word spread within wave) x cols {n4, n4+64}
  int kg = 2 * (lane >> 4) + 8 * wv;    // {0,2,4,6}+8w -> all 16 k-pairs across 4 waves
  int n4 = 4 * (lane & 15);
  const float* Br0 = Bb + (size_t)kg * ND + n4;
  const float* Br1 = Bb + (size_t)(kg + 1) * ND + n4;

  unsigned aoff[4];
#pragma unroll
  for (int mf = 0; mf < 4; mf++)
    aoff[mf] = (wm + mf * 16 + (lane & 15)) * 64 + ((lane >> 4) << 4);

  int wo[8];
#pragma unroll
  for (int h = 0; h < 2; h++)
#pragma unroll
    for (int q = 0; q < 4; q++) {
      int n = n4 + 64 * h + q;
      wo[h * 4 + q] = n * 64 + (((kg >> 3) ^ swz3(n)) << 4) + (kg & 7) * 2;
    }

  half8 afA[4], afB[4], bf[4];
  f32x4 E0, E1, E2, E3, O0, O1, O2, O3;

#define LOADB(tt, S0, S1, S2, S3) { size_t _o = (size_t)(tt) * 32 * ND; \
    S0 = *(const f32x4*)(Br0 + _o);      S1 = *(const f32x4*)(Br1 + _o); \
    S2 = *(const f32x4*)(Br0 + _o + 64); S3 = *(const f32x4*)(Br1 + _o + 64); }

#define WRITEB(S0, S1, S2, S3, par) { char* _b = lds + (par) * 8192; \
    _Pragma("unroll") for (int _q = 0; _q < 4; _q++) { \
      half2v _h; _h[0] = (f16)S0[_q]; _h[1] = (f16)S1[_q]; \
      *(half2v*)(_b + wo[_q]) = _h; } \
    _Pragma("unroll") for (int _q = 0; _q < 4; _q++) { \
      half2v _h; _h[0] = (f16)S2[_q]; _h[1] = (f16)S3[_q]; \
      *(half2v*)(_b + wo[4 + _q]) = _h; } }

#define BFREAD(par) { _Pragma("unroll") for (int _f = 0; _f < 4; _f++) { \
      int _n = wn + _f * 16 + (lane & 15); \
      bf[_f] = *(const half8*)(lds + (par) * 8192 + _n * 64 + (((lane >> 4) ^ swz3(_n)) << 4)); } }

#define LOADA(tt, AF) { _Pragma("unroll") for (int _m = 0; _m < 4; _m++) \
      AF[_m] = *(const half8*)(Ab + (size_t)(tt) * tsA + aoff[_m]); }

#define DOMFMA(AF) { _Pragma("unroll") for (int _m = 0; _m < 4; _m++) \
      _Pragma("unroll") for (int _f = 0; _f < 4; _f++) \
        acc[_m][_f] = __builtin_amdgcn_mfma_f32_16x16x32_f16(AF[_m], bf[_f], acc[_m][_f], 0, 0, 0); }

  LOADB(0, E0, E1, E2, E3)
  LOADB(1, O0, O1, O2, O3)
  WRITEB(E0, E1, E2, E3, 0)
  LOADA(0, afA)
  SYNC()

  for (int t = 0; t < NKt; t += 2) {
    BFREAD(0)
    LOADA(t + 1, afB)
    WRITEB(O0, O1, O2, O3, 1)
    if (t + 2 < NKt) LOADB(t + 2, E0, E1, E2, E3)
    DOMFMA(afA)
    SYNC()
    BFREAD(1)
    if (t + 2 < NKt) {
      LOADA(t + 2, afA)
      WRITEB(E0, E1, E2, E3, 0)
      if (t + 3 < NKt) LOADB(t + 3, O0, O1, O2, O3)
    }
    DOMFMA(afB)
    if (t + 2 < NKt) SYNC()
  }

#undef LOADB
#undef WRITEB
#undef BFREAD
#undef LOADA
#undef DOMFMA
}

// ---------------- fused up: routed g/u (2048 blk) + shared g/u (512 blk) ----------------
__global__ __launch_bounds__(256, 2) void fused_up_kernel(
    const f16* __restrict__ xg, const f16* __restrict__ xbt,
    const float* __restrict__ w1, const float* __restrict__ w3,
    const float* __restrict__ sg, const float* __restrict__ su,
    f16* __restrict__ hg, f16* __restrict__ hu,
    f16* __restrict__ hsg, f16* __restrict__ hsu,
    const int* __restrict__ cnt, const int* __restrict__ offs) {
  __shared__ __align__(16) char lds[16384];
  int bid = blockIdx.x;
  int tid = threadIdx.x, lane = tid & 63, wv = tid >> 6;
  int wm = (wv >> 1) * 64, wn = (wv & 1) * 64, koff = (lane >> 4) << 2;

  f32x4 acc[4][4];
#pragma unroll
  for (int mf = 0; mf < 4; mf++)
#pragma unroll
    for (int nf = 0; nf < 4; nf++) acc[mf][nf] = (f32x4){0.f, 0.f, 0.f, 0.f};

  if (bid < 2048) {
    int elo = bid & 7, n = (bid >> 3) & 7, m = (bid >> 6) & 3, ehi = (bid >> 8) & 3, mat = bid >> 10;
    int e = elo + ehi * 8;
    int ce = cnt[e];
    int m0 = m * 128;
    if (m0 >= ce) return;
    int oe = offs[e];
    const char* Ab = (const char*)xg + (size_t)oe * 4096 + m0 * 64;
    const float* B = (mat ? w3 : w1) + (size_t)e * 2048 * 1024 + n * 128;
    core128(Ab, ce * 64, 64, B, 1024, lds, acc);
    char* Hb = (char*)(mat ? hu : hg) + (size_t)oe * 2048;
    size_t kts = (size_t)ce * 64;
#pragma unroll
    for (int mf = 0; mf < 4; mf++)
#pragma unroll
      for (int j = 0; j < 4; j++) {
        int gs = m0 + wm + mf * 16 + koff + j;
        if (gs < ce) {
#pragma unroll
          for (int nf = 0; nf < 4; nf++) {
            int gc = n * 128 + wn + nf * 16 + (lane & 15);
            *(f16*)(Hb + (size_t)(gc >> 5) * kts + gs * 64 + (gc & 31) * 2) = (f16)acc[mf][nf][j];
          }
        }
      }
  } else {
    int b2 = bid - 2048;
    int mat = b2 >> 8, rem = b2 & 255, m = rem >> 4, n = rem & 15;
    int m0 = m * 128;
    const char* Ab = (const char*)xbt + m0 * 64;
    const float* B = (mat ? su : sg) + n * 128;
    core128(Ab, 131072, 64, B, 2048, lds, acc);
    char* Hb = (char*)(mat ? hsu : hsg);
#pragma unroll
    for (int mf = 0; mf < 4; mf++)
#pragma unroll
      for (int j = 0; j < 4; j++) {
        int gs = m0 + wm + mf * 16 + koff + j;
#pragma unroll
        for (int nf = 0; nf < 4; nf++) {
          int gc = n * 128 + wn + nf * 16 + (lane & 15);
          *(f16*)(Hb + (size_t)(gc >> 5) * 131072 + gs * 64 + (gc & 31) * 2) = (f16)acc[mf][nf][j];
        }
      }
  }
}

// ---------------- combine: h = silu(g) * u ----------------
__global__ __launch_bounds__(256) void combine_kernel(
    const f16* __restrict__ hg, const f16* __restrict__ hu, f16* __restrict__ hbuf,
    const f16* __restrict__ hsg, const f16* __restrict__ hsu, f16* __restrict__ hs) {
  size_t i = ((size_t)blockIdx.x * 256 + threadIdx.x) * 8;
  const f16 *gp, *up;
  f16* op;
  if (i < 8388608) { gp = hg + i; up = hu + i; op = hbuf + i; }
  else { size_t j = i - 8388608; gp = hsg + j; up = hsu + j; op = hs + j; }
  half8 g = *(const half8*)gp;
  half8 u = *(const half8*)up;
  half8 o;
#pragma unroll
  for (int k = 0; k < 8; k++) {
    float gv = (float)g[k];
    float uv = (float)u[k];
    o[k] = (f16)(gv / (1.f + expf(-gv)) * uv);
  }
  *(half8*)op = o;
}

// ---------------- fused down: routed (2048 blk) + shared (256 blk), atomics ----------------
__global__ __launch_bounds__(256, 2) void fused_down_kernel(
    const f16* __restrict__ hbuf, const f16* __restrict__ hs,
    const float* __restrict__ w2, const float* __restrict__ sd,
    float* __restrict__ out, const int* __restrict__ tok,
    const float* __restrict__ wt, const int* __restrict__ cnt,
    const int* __restrict__ offs) {
  __shared__ __align__(16) char lds[16384];
  int bid = blockIdx.x;
  int tid = threadIdx.x, lane = tid & 63, wv = tid >> 6;
  int wm = (wv >> 1) * 64, wn = (wv & 1) * 64, koff = (lane >> 4) << 2;

  f32x4 acc[4][4];
#pragma unroll
  for (int mf = 0; mf < 4; mf++)
#pragma unroll
    for (int nf = 0; nf < 4; nf++) acc[mf][nf] = (f32x4){0.f, 0.f, 0.f, 0.f};

  if (bid < 2048) {
    int elo = bid & 7, n = (bid >> 3) & 15, m = (bid >> 7) & 3, ehi = (bid >> 9) & 3;
    int e = elo + ehi * 8;
    int ce = cnt[e];
    int m0 = m * 128;
    if (m0 >= ce) return;
    int oe = offs[e];
    const char* Ab = (const char*)hbuf + (size_t)oe * 2048 + m0 * 64;
    const float* B = w2 + (size_t)e * 1024 * 2048 + n * 128;
    core128(Ab, ce * 64, 32, B, 2048, lds, acc);
    const int* tokp = tok + e * CAP;
    const float* wtp = wt + e * CAP;
#pragma unroll
    for (int mf = 0; mf < 4; mf++)
#pragma unroll
      for (int j = 0; j < 4; j++) {
        int gs = m0 + wm + mf * 16 + koff + j;
        if (gs < ce) {
          int tk = tokp[gs];
          float w = wtp[gs];
#pragma unroll
          for (int nf = 0; nf < 4; nf++) {
            int gc = n * 128 + wn + nf * 16 + (lane & 15);
            atomicAdd(out + (size_t)tk * HDIM + gc, acc[mf][nf][j] * w);
          }
        }
      }
  } else {
    int b2 = bid - 2048;
    int m = b2 >> 4, n = b2 & 15;
    int m0 = m * 128;
    const char* Ab = (const char*)hs + m0 * 64;
    const float* B = sd + n * 128;
    core128(Ab, 131072, 64, B, 2048, lds, acc);
#pragma unroll
    for (int mf = 0; mf < 4; mf++)
#pragma unroll
      for (int j = 0; j < 4; j++) {
        int gs = m0 + wm + mf * 16 + koff + j;
#pragma unroll
        for (int nf = 0; nf < 4; nf++) {
          int gc = n * 128 + wn + nf * 16 + (lane & 15);
          atomicAdd(out + (size_t)gs * HDIM + gc, acc[mf][nf][j]);
        }
      }
  }
}

// ---------------- launch ----------------
extern "C" void kernel_launch(void* const* d_in, const int* in_sizes, int n_in,
                              void* d_out, int out_size, void* d_ws, size_t ws_size,
                              hipStream_t stream) {
  const float* x  = (const float*)d_in[0];
  const float* gw = (const float*)d_in[1];
  const float* gb = (const float*)d_in[2];
  const float* w1 = (const float*)d_in[3];
  const float* w2 = (const float*)d_in[4];
  const float* w3 = (const float*)d_in[5];
  const float* sg = (const float*)d_in[6];
  const float* su = (const float*)d_in[7];
  const float* sd = (const float*)d_in[8];
  float* out = (float*)d_out;
  char* ws = (char*)d_ws;

  f16*   xbt  = (f16*)(ws);                  // 8 MB
  f16*   hsg  = (f16*)(ws + 8388608);        // 8 MB
  f16*   hsu  = (f16*)(ws + 16777216);       // 8 MB
  f16*   hs   = (f16*)(ws + 25165824);       // 8 MB
  f16*   hg   = (f16*)(ws + 33554432);       // 16 MB
  f16*   hu   = (f16*)(ws + 50331648);       // 16 MB
  f16*   xg   = (f16*)(ws + 67108864);       // 32 MB + slack
  f16*   hbuf = (f16*)(ws + 67108864);       // 16 MB (aliases xg; disjoint lifetime)
  int*   tok  = (int*)(ws + 101711872);
  float* wt   = (float*)(ws + 101777408);
  int*   tidx = (int*)(ws + 101842944);
  float* tw   = (float*)(ws + 101875712);
  int*   cnt  = (int*)(ws + 101908480);
  int*   offs = (int*)(ws + 101908608);

  gateconv_kernel<<<2048, 256, 0, stream>>>(x, gw, gb, tidx, tw, xbt);
  dispatch_kernel<<<32, 256, 0, stream>>>(tidx, tw, tok, wt, cnt);
  scan_kernel<<<1, 32, 0, stream>>>(cnt, offs);
  gather_kernel<<<2048, 256, 0, stream>>>(xbt, tok, cnt, offs, xg);

  fused_up_kernel<<<2560, 256, 0, stream>>>(xg, xbt, w1, w3, sg, su,
                                            hg, hu, hsg, hsu, cnt, offs);
  combine_kernel<<<6144, 256, 0, stream>>>(hg, hu, hbuf, hsg, hsu, hs);

  hipMemsetAsync(out, 0, (size_t)out_size * sizeof(float), stream);
  fused_down_kernel<<<2304, 256, 0, stream>>>(hbuf, hs, w2, sd, out, tok, wt, cnt, offs);
}